// Round 4
// baseline (123.455 us; speedup 1.0000x reference)
//
#include <hip/hip_runtime.h>

// 3D Haar DWT (analysis), B=2, N=128, C=4.
// out[n,a,b,d, c+4*chunk], chunks = [LLL,LLH,LHL,LHH,HLL,HLH,HHL,HHH]
// with selectors (sa,sb,sd) = [(0,0,0),(1,0,0),(0,1,0),(1,1,0),
//                              (0,0,1),(1,1,1),(0,1,1),(1,1,1)]
// (HLH==HHH==(1,1,1) per the reference's slicing — intentional.)

__device__ __forceinline__ float4 lin(float c0, const float4& u, float c1, const float4& v) {
    return make_float4(fmaf(c0, u.x, c1 * v.x),
                       fmaf(c0, u.y, c1 * v.y),
                       fmaf(c0, u.z, c1 * v.z),
                       fmaf(c0, u.w, c1 * v.w));
}

__global__ __launch_bounds__(256) void dwt3d_haar_kernel(
        const float* __restrict__ x,   // (2,128,128,128,4) f32
        const float* __restrict__ A,   // (128,128) f32 analysis bank
        float* __restrict__ out) {     // (2,64,64,64,32) f32
    const int t = blockIdx.x * blockDim.x + threadIdx.x;
    const int d = t & 63;
    const int b = (t >> 6) & 63;
    const int a = (t >> 12) & 63;
    const int n = t >> 18;

    // Filter taps straight from A (lowpass row 0, highpass row 64).
    const float h00 = A[0];              // h0[0]
    const float h01 = A[1];              // h0[1]
    const float h10 = A[64 * 128 + 0];   // h1[0]
    const float h11 = A[64 * 128 + 1];   // h1[1]

    const float4* __restrict__ x4 = reinterpret_cast<const float4*>(x);
    float4* __restrict__ o4 = reinterpret_cast<float4*>(out);

    // Input strides in float4 units: n:2097152, i:16384, j:128, k:1
    const int ib = n * 2097152 + a * 32768 + b * 256 + d * 2;

    float4 p[2][2][2];
    #pragma unroll
    for (int i = 0; i < 2; ++i) {
        #pragma unroll
        for (int j = 0; j < 2; ++j) {
            const int o = ib + i * 16384 + j * 128;
            p[i][j][0] = x4[o];
            p[i][j][1] = x4[o + 1];
        }
    }

    // Stage 1: transform along i (first spatial axis) -> selector sa
    float4 A0[2][2], A1[2][2];
    #pragma unroll
    for (int j = 0; j < 2; ++j) {
        #pragma unroll
        for (int k = 0; k < 2; ++k) {
            A0[j][k] = lin(h00, p[0][j][k], h01, p[1][j][k]);
            A1[j][k] = lin(h10, p[0][j][k], h11, p[1][j][k]);
        }
    }

    // Stage 2: along j -> selector sb
    float4 B00[2], B01[2], B10[2], B11[2];
    #pragma unroll
    for (int k = 0; k < 2; ++k) {
        B00[k] = lin(h00, A0[0][k], h01, A0[1][k]);
        B01[k] = lin(h10, A0[0][k], h11, A0[1][k]);
        B10[k] = lin(h00, A1[0][k], h01, A1[1][k]);
        B11[k] = lin(h10, A1[0][k], h11, A1[1][k]);
    }

    // Stage 3: along k -> selector sd  (v_{sa sb sd})
    const float4 v000 = lin(h00, B00[0], h01, B00[1]);
    const float4 v001 = lin(h10, B00[0], h11, B00[1]);
    const float4 v010 = lin(h00, B01[0], h01, B01[1]);
    const float4 v011 = lin(h10, B01[0], h11, B01[1]);
    const float4 v100 = lin(h00, B10[0], h01, B10[1]);
    const float4 v110 = lin(h00, B11[0], h01, B11[1]);
    const float4 v111 = lin(h10, B11[0], h11, B11[1]);
    // v101 is never emitted by the reference's slicing.

    // Output strides in float4 units: n:2097152, a:32768, b:512, d:8, chunk:1
    const int ob = n * 2097152 + a * 32768 + b * 512 + d * 8;
    o4[ob + 0] = v000;  // LLL
    o4[ob + 1] = v100;  // LLH
    o4[ob + 2] = v010;  // LHL
    o4[ob + 3] = v110;  // LHH
    o4[ob + 4] = v001;  // HLL
    o4[ob + 5] = v111;  // HLH (== (1,1,1) per reference)
    o4[ob + 6] = v011;  // HHL
    o4[ob + 7] = v111;  // HHH
}

extern "C" void kernel_launch(void* const* d_in, const int* in_sizes, int n_in,
                              void* d_out, int out_size, void* d_ws, size_t ws_size,
                              hipStream_t stream) {
    const float* x = (const float*)d_in[0];
    const float* A = (const float*)d_in[1];
    float* out = (float*)d_out;

    // 2 * 64^3 = 524288 threads, one per 2x2x2 block.
    const int total = 2 * 64 * 64 * 64;
    const int block = 256;
    const int grid = total / block;  // 2048
    hipLaunchKernelGGL(dwt3d_haar_kernel, dim3(grid), dim3(block), 0, stream,
                       x, A, out);
}

// Round 5
// 108.898 us; speedup vs baseline: 1.1337x; 1.1337x over previous
//
#include <hip/hip_runtime.h>

// 3D Haar DWT (analysis), B=2, N=128, C=4 — shuffle-butterfly version.
// One thread per OUTPUT float4 (one subband chunk c of one (n,a,b,d) block).
// Loads: per-wave 4x256B dense segments. Stores: per-wave 1KB dense.
// Butterfly stage order i (mask 1) -> k (mask 4) -> j (mask 2) so the
// reference's HLH==HHH==(1,1,1) slicing quirk is a per-lane coefficient
// select in the final stage (sb = j0 || c==5).

__device__ __forceinline__ float4 lin(float c0, const float4& u, float c1, const float4& v) {
    return make_float4(fmaf(c0, u.x, c1 * v.x),
                       fmaf(c0, u.y, c1 * v.y),
                       fmaf(c0, u.z, c1 * v.z),
                       fmaf(c0, u.w, c1 * v.w));
}

__device__ __forceinline__ float4 shfl_xor4(const float4& v, int mask) {
    return make_float4(__shfl_xor(v.x, mask),
                       __shfl_xor(v.y, mask),
                       __shfl_xor(v.z, mask),
                       __shfl_xor(v.w, mask));
}

__global__ __launch_bounds__(256) void dwt3d_haar_bfly(
        const float* __restrict__ x,   // (2,128,128,128,4) f32
        const float* __restrict__ A,   // (128,128) f32 analysis bank
        float* __restrict__ out) {     // (2,64,64,64,32) f32
    const int t = blockIdx.x * blockDim.x + threadIdx.x;
    // Output float4 linear index == t. Decode:
    const int c = t & 7;           // subband chunk
    const int d = (t >> 3) & 63;
    const int b = (t >> 9) & 63;
    const int a = (t >> 15) & 63;
    const int n = t >> 21;

    // Filter taps from A (lowpass row 0, highpass row 64) — scalar/uniform.
    const float h00 = A[0];
    const float h01 = A[1];
    const float h10 = A[64 * 128 + 0];
    const float h11 = A[64 * 128 + 1];

    // This lane's input element of the 2x2x2 block:
    const int i0 = c & 1;
    const int j0 = (c >> 1) & 1;
    const int k0 = (c >> 2) & 1;

    const float4* __restrict__ x4 = reinterpret_cast<const float4*>(x);
    // Input float4 strides: n:2097152, i:16384, j:128, k:1.
    const int xi = n * 2097152 + a * 32768 + b * 256 + d * 2
                 + i0 * 16384 + j0 * 128 + k0;
    float4 v = x4[xi];

    // Stage 1 — reduce axis i (partner lane ^1). Selector sa = i0.
    {
        const float4 w = shfl_xor4(v, 1);
        const float4 p0 = i0 ? w : v;
        const float4 p1 = i0 ? v : w;
        const float c0 = i0 ? h10 : h00;
        const float c1 = i0 ? h11 : h01;
        v = lin(c0, p0, c1, p1);   // -> A_{sa}[j0][k0]
    }
    // Stage 2 — reduce axis k (partner lane ^4). Selector sd = k0.
    {
        const float4 w = shfl_xor4(v, 4);
        const float4 p0 = k0 ? w : v;
        const float4 p1 = k0 ? v : w;
        const float c0 = k0 ? h10 : h00;
        const float c1 = k0 ? h11 : h01;
        v = lin(c0, p0, c1, p1);   // -> C_{sa,sd}[j0]
    }
    // Stage 3 — reduce axis j (partner lane ^2).
    // Selector sb = j0, EXCEPT chunk 5 (HLH in the reference's slicing)
    // which takes (1,1,1): force sb=1 there. Pairing uses j0 only.
    {
        const float4 w = shfl_xor4(v, 2);
        const float4 p0 = j0 ? w : v;
        const float4 p1 = j0 ? v : w;
        const int sb = j0 | (c == 5 ? 1 : 0);
        const float c0 = sb ? h10 : h00;
        const float c1 = sb ? h11 : h01;
        v = lin(c0, p0, c1, p1);   // -> v_{sa,sb,sd}
    }

    // Store: out float4 index == t -> fully coalesced 1KB/wave.
    reinterpret_cast<float4*>(out)[t] = v;
}

extern "C" void kernel_launch(void* const* d_in, const int* in_sizes, int n_in,
                              void* d_out, int out_size, void* d_ws, size_t ws_size,
                              hipStream_t stream) {
    const float* x = (const float*)d_in[0];
    const float* A = (const float*)d_in[1];
    float* out = (float*)d_out;

    // One thread per output float4: 2*64^3*8 = 4,194,304 threads.
    const int total = 2 * 64 * 64 * 64 * 8;
    const int block = 256;
    const int grid = total / block;  // 16384
    hipLaunchKernelGGL(dwt3d_haar_bfly, dim3(grid), dim3(block), 0, stream,
                       x, A, out);
}